// Round 9
// baseline (169.682 us; speedup 1.0000x reference)
//
#include <hip/hip_runtime.h>

#define KNB 8
#define OCC_R 0.25f
#define TILE 1024
#define BIGF 1e30f

__device__ __forceinline__ float med3f(float a, float b, float c) {
#if defined(__has_builtin) && __has_builtin(__builtin_amdgcn_fmed3f)
    return __builtin_amdgcn_fmed3f(a, b, c);   // single v_med3_f32
#else
    return fmaxf(fminf(a, b), fminf(fmaxf(a, b), c));
#endif
}

// Unconditional parallel insert of x into sorted-ascending P0..P7 (drops old P7).
// All 8 med3 read only OLD values -> mutually independent (good ILP).
#define INS8P(P, val) { float x = (val);      \
    P##7 = med3f(P##6, P##7, x);              \
    P##6 = med3f(P##5, P##6, x);              \
    P##5 = med3f(P##4, P##5, x);              \
    P##4 = med3f(P##3, P##4, x);              \
    P##3 = med3f(P##2, P##3, x);              \
    P##2 = med3f(P##1, P##2, x);              \
    P##1 = med3f(P##0, P##1, x);              \
    P##0 = fminf(P##0, x); }

// ---------------- kernel 1: prep targets -> (-2x, -2y, -2z, x^2+y^2+z^2)
__global__ void prep_targets(const float* __restrict__ tc, float4* __restrict__ out, int M) {
    int j = blockIdx.x * blockDim.x + threadIdx.x;
    if (j >= M) return;
    float x = tc[3 * j + 0];
    float y = tc[3 * j + 1];
    float z = tc[3 * j + 2];
    float k2 = x * x + y * y + z * z;
    out[j] = make_float4(-2.0f * x, -2.0f * y, -2.0f * z, k2);
}

// ---------------- kernel 2: top-8 for TWO queries per thread over a target chunk.
// One broadcast ds_read_b128 per candidate now feeds 26 VALU ops (two ladders),
// moving the bottleneck off the CU-shared LDS pipe (12 cyc/ds_read) onto VALU
// issue (13 CU-cyc per candidate-wave-iter).
__global__ __launch_bounds__(256) void knn_partial(
    const float* __restrict__ tf,     // to_filter, N x 6
    const float4* __restrict__ tgt,   // prepped targets, M
    float* __restrict__ part,         // N x split x 8 (squared dists, sorted asc)
    int N, int M) {
    __shared__ float4 tile[TILE];

    int half = N >> 1;
    int qa = blockIdx.x * blockDim.x + threadIdx.x;   // first query
    int qb = qa + half;                               // second query
    int s = blockIdx.y;                               // split index
    int nspl = gridDim.y;
    int chunk = M / nspl;                             // 1024 at split=16
    int c0 = s * chunk;

    float qax = tf[6 * qa + 0], qay = tf[6 * qa + 1], qaz = tf[6 * qa + 2];
    float qbx = tf[6 * qb + 0], qby = tf[6 * qb + 1], qbz = tf[6 * qb + 2];
    float qa2 = qax * qax + qay * qay + qaz * qaz;
    float qb2 = qbx * qbx + qby * qby + qbz * qbz;

    float A0 = BIGF, A1 = BIGF, A2 = BIGF, A3 = BIGF;
    float A4 = BIGF, A5 = BIGF, A6 = BIGF, A7 = BIGF;
    float B0 = BIGF, B1 = BIGF, B2 = BIGF, B3 = BIGF;
    float B4 = BIGF, B5 = BIGF, B6 = BIGF, B7 = BIGF;

    for (int base = c0; base < c0 + chunk; base += TILE) {
        __syncthreads();
        for (int t = threadIdx.x; t < TILE; t += 256) {
            tile[t] = tgt[base + t];
        }
        __syncthreads();
        #pragma unroll 4
        for (int t = 0; t < TILE; ++t) {
            float4 c = tile[t];
            float da = qa2 + c.w;
            da = fmaf(c.x, qax, da);
            da = fmaf(c.y, qay, da);
            da = fmaf(c.z, qaz, da);
            float db = qb2 + c.w;
            db = fmaf(c.x, qbx, db);
            db = fmaf(c.y, qby, db);
            db = fmaf(c.z, qbz, db);
            INS8P(A, da);
            INS8P(B, db);
        }
    }

    float* pa = part + ((size_t)qa * nspl + s) * KNB;
    ((float4*)pa)[0] = make_float4(A0, A1, A2, A3);
    ((float4*)pa)[1] = make_float4(A4, A5, A6, A7);
    float* pb = part + ((size_t)qb * nspl + s) * KNB;
    ((float4*)pb)[0] = make_float4(B0, B1, B2, B3);
    ((float4*)pb)[1] = make_float4(B4, B5, B6, B7);
}

// ---------------- kernel 3: merge split partial lists, sqrt, mask, store
__global__ void knn_merge(const float* __restrict__ part, float* __restrict__ out,
                          int N, int split) {
    int q = blockIdx.x * blockDim.x + threadIdx.x;
    if (q >= N) return;
    const float4* p = (const float4*)(part + (size_t)q * split * KNB);
    float4 v0 = p[0];
    float4 v1 = p[1];
    float A0 = v0.x, A1 = v0.y, A2 = v0.z, A3 = v0.w;
    float A4 = v1.x, A5 = v1.y, A6 = v1.z, A7 = v1.w;
    for (int s = 1; s < split; ++s) {
        float4 u0 = p[2 * s];
        float4 u1 = p[2 * s + 1];
        INS8P(A, u0.x); INS8P(A, u0.y); INS8P(A, u0.z); INS8P(A, u0.w);
        INS8P(A, u1.x); INS8P(A, u1.y); INS8P(A, u1.z); INS8P(A, u1.w);
    }
    float d0 = sqrtf(fmaxf(A0, 0.0f));
    float d1 = sqrtf(fmaxf(A1, 0.0f));
    float d2_ = sqrtf(fmaxf(A2, 0.0f));
    float d3 = sqrtf(fmaxf(A3, 0.0f));
    float d4 = sqrtf(fmaxf(A4, 0.0f));
    float d5 = sqrtf(fmaxf(A5, 0.0f));
    float d6 = sqrtf(fmaxf(A6, 0.0f));
    float d7 = sqrtf(fmaxf(A7, 0.0f));
    bool good = d0 > OCC_R;
    float m = good ? 1.0f : 0.0f;
    float4* o = (float4*)(out + (size_t)q * KNB);
    o[0] = make_float4(d0 * m, d1 * m, d2_ * m, d3 * m);
    o[1] = make_float4(d4 * m, d5 * m, d6 * m, d7 * m);
}

extern "C" void kernel_launch(void* const* d_in, const int* in_sizes, int n_in,
                              void* d_out, int out_size, void* d_ws, size_t ws_size,
                              hipStream_t stream) {
    const float* tf = (const float*)d_in[0];   // to_filter (N x 6)
    const float* tc = (const float*)d_in[1];   // target_coords (M x 3)
    int N = in_sizes[0] / 6;                   // 32768
    int M = in_sizes[1] / 3;                   // 16384
    float* outp = (float*)d_out;

    char* ws = (char*)d_ws;
    size_t tgt_bytes = ((size_t)M * 16 + 255) & ~(size_t)255;
    float4* tgt = (float4*)ws;
    float* part = (float*)(ws + tgt_bytes);

    int split = 16;
    while (split > 1 && ws_size < tgt_bytes + (size_t)N * split * KNB * 4) split >>= 1;

    prep_targets<<<(M + 255) / 256, 256, 0, stream>>>(tc, tgt, M);
    // 2 queries per thread: grid x = N/2/256
    dim3 grid(N / 512, split);
    knn_partial<<<grid, 256, 0, stream>>>(tf, tgt, part, N, M);
    knn_merge<<<(N + 255) / 256, 256, 0, stream>>>(part, outp, N, split);
}

// Round 10
// 166.215 us; speedup vs baseline: 1.0209x; 1.0209x over previous
//
#include <hip/hip_runtime.h>

#define KNB 8
#define OCC_R 0.25f
#define TILE 512
#define BIGF 1e30f

__device__ __forceinline__ float med3f(float a, float b, float c) {
#if defined(__has_builtin) && __has_builtin(__builtin_amdgcn_fmed3f)
    return __builtin_amdgcn_fmed3f(a, b, c);   // single v_med3_f32
#else
    return fmaxf(fminf(a, b), fminf(fmaxf(a, b), c));
#endif
}

// Unconditional parallel insert of x into sorted-ascending P0..P7 (drops old P7).
// All 8 med3 read only OLD values -> mutually independent (good ILP).
#define INS8P(P, val) { float x = (val);      \
    P##7 = med3f(P##6, P##7, x);              \
    P##6 = med3f(P##5, P##6, x);              \
    P##5 = med3f(P##4, P##5, x);              \
    P##4 = med3f(P##3, P##4, x);              \
    P##3 = med3f(P##2, P##3, x);              \
    P##2 = med3f(P##1, P##2, x);              \
    P##1 = med3f(P##0, P##1, x);              \
    P##0 = fminf(P##0, x); }

// ---------------- kernel 1: prep targets -> (-2x, -2y, -2z, x^2+y^2+z^2)
__global__ void prep_targets(const float* __restrict__ tc, float4* __restrict__ out, int M) {
    int j = blockIdx.x * blockDim.x + threadIdx.x;
    if (j >= M) return;
    float x = tc[3 * j + 0];
    float y = tc[3 * j + 1];
    float z = tc[3 * j + 2];
    float k2 = x * x + y * y + z * z;
    out[j] = make_float4(-2.0f * x, -2.0f * y, -2.0f * z, k2);
}

// ---------------- kernel 2: top-8 for TWO queries per thread over a target chunk.
// One broadcast ds_read_b128 feeds 26 VALU (two ladders): LDS-pipe demand 12
// CU-cyc/iter vs VALU 13 CU-cyc/iter. split=32 keeps 2048 blocks = 8 blocks/CU
// = 32 waves/CU so the dependent chains actually overlap (R9 lesson: the same
// amortization at 16 waves/CU ran latency-bound at 27 cyc/iter).
__global__ __launch_bounds__(256) void knn_partial(
    const float* __restrict__ tf,     // to_filter, N x 6
    const float4* __restrict__ tgt,   // prepped targets, M
    float* __restrict__ part,         // N x split x 8 (squared dists, sorted asc)
    int N, int M) {
    __shared__ float4 tile[TILE];

    int half = N >> 1;
    int qa = blockIdx.x * blockDim.x + threadIdx.x;   // first query
    int qb = qa + half;                               // second query
    int s = blockIdx.y;                               // split index
    int nspl = gridDim.y;
    int chunk = M / nspl;                             // 512 at split=32
    int c0 = s * chunk;

    float qax = tf[6 * qa + 0], qay = tf[6 * qa + 1], qaz = tf[6 * qa + 2];
    float qbx = tf[6 * qb + 0], qby = tf[6 * qb + 1], qbz = tf[6 * qb + 2];
    float qa2 = qax * qax + qay * qay + qaz * qaz;
    float qb2 = qbx * qbx + qby * qby + qbz * qbz;

    float A0 = BIGF, A1 = BIGF, A2 = BIGF, A3 = BIGF;
    float A4 = BIGF, A5 = BIGF, A6 = BIGF, A7 = BIGF;
    float B0 = BIGF, B1 = BIGF, B2 = BIGF, B3 = BIGF;
    float B4 = BIGF, B5 = BIGF, B6 = BIGF, B7 = BIGF;

    for (int base = c0; base < c0 + chunk; base += TILE) {
        __syncthreads();
        for (int t = threadIdx.x; t < TILE; t += 256) {
            tile[t] = tgt[base + t];
        }
        __syncthreads();
        #pragma unroll 4
        for (int t = 0; t < TILE; ++t) {
            float4 c = tile[t];
            float da = qa2 + c.w;
            da = fmaf(c.x, qax, da);
            da = fmaf(c.y, qay, da);
            da = fmaf(c.z, qaz, da);
            float db = qb2 + c.w;
            db = fmaf(c.x, qbx, db);
            db = fmaf(c.y, qby, db);
            db = fmaf(c.z, qbz, db);
            INS8P(A, da);
            INS8P(B, db);
        }
    }

    float* pa = part + ((size_t)qa * nspl + s) * KNB;
    ((float4*)pa)[0] = make_float4(A0, A1, A2, A3);
    ((float4*)pa)[1] = make_float4(A4, A5, A6, A7);
    float* pb = part + ((size_t)qb * nspl + s) * KNB;
    ((float4*)pb)[0] = make_float4(B0, B1, B2, B3);
    ((float4*)pb)[1] = make_float4(B4, B5, B6, B7);
}

// ---------------- kernel 3: merge split partial lists, sqrt, mask, store
__global__ void knn_merge(const float* __restrict__ part, float* __restrict__ out,
                          int N, int split) {
    int q = blockIdx.x * blockDim.x + threadIdx.x;
    if (q >= N) return;
    const float4* p = (const float4*)(part + (size_t)q * split * KNB);
    float4 v0 = p[0];
    float4 v1 = p[1];
    float A0 = v0.x, A1 = v0.y, A2 = v0.z, A3 = v0.w;
    float A4 = v1.x, A5 = v1.y, A6 = v1.z, A7 = v1.w;
    for (int s = 1; s < split; ++s) {
        float4 u0 = p[2 * s];
        float4 u1 = p[2 * s + 1];
        INS8P(A, u0.x); INS8P(A, u0.y); INS8P(A, u0.z); INS8P(A, u0.w);
        INS8P(A, u1.x); INS8P(A, u1.y); INS8P(A, u1.z); INS8P(A, u1.w);
    }
    float d0 = sqrtf(fmaxf(A0, 0.0f));
    float d1 = sqrtf(fmaxf(A1, 0.0f));
    float d2_ = sqrtf(fmaxf(A2, 0.0f));
    float d3 = sqrtf(fmaxf(A3, 0.0f));
    float d4 = sqrtf(fmaxf(A4, 0.0f));
    float d5 = sqrtf(fmaxf(A5, 0.0f));
    float d6 = sqrtf(fmaxf(A6, 0.0f));
    float d7 = sqrtf(fmaxf(A7, 0.0f));
    bool good = d0 > OCC_R;
    float m = good ? 1.0f : 0.0f;
    float4* o = (float4*)(out + (size_t)q * KNB);
    o[0] = make_float4(d0 * m, d1 * m, d2_ * m, d3 * m);
    o[1] = make_float4(d4 * m, d5 * m, d6 * m, d7 * m);
}

extern "C" void kernel_launch(void* const* d_in, const int* in_sizes, int n_in,
                              void* d_out, int out_size, void* d_ws, size_t ws_size,
                              hipStream_t stream) {
    const float* tf = (const float*)d_in[0];   // to_filter (N x 6)
    const float* tc = (const float*)d_in[1];   // target_coords (M x 3)
    int N = in_sizes[0] / 6;                   // 32768
    int M = in_sizes[1] / 3;                   // 16384
    float* outp = (float*)d_out;

    char* ws = (char*)d_ws;
    size_t tgt_bytes = ((size_t)M * 16 + 255) & ~(size_t)255;
    float4* tgt = (float4*)ws;
    float* part = (float*)(ws + tgt_bytes);

    // split=32, 2 queries/thread -> grid 64x32 = 2048 blocks = 8 blocks/CU.
    int split = 32;
    while (split > 1 && ws_size < tgt_bytes + (size_t)N * split * KNB * 4) split >>= 1;

    prep_targets<<<(M + 255) / 256, 256, 0, stream>>>(tc, tgt, M);
    dim3 grid(N / 512, split);
    knn_partial<<<grid, 256, 0, stream>>>(tf, tgt, part, N, M);
    knn_merge<<<(N + 255) / 256, 256, 0, stream>>>(part, outp, N, split);
}